// Round 1
// baseline (363.709 us; speedup 1.0000x reference)
//
#include <hip/hip_runtime.h>
#include <math.h>

#define IN_F 4096
#define OUT_F 4096
#define BATCH 256
#define TSTEPS 8

#define BM 128
#define BN 128
#define BK 32
#define KSPLIT 4
#define KLEN (IN_F / KSPLIT) /* 1024 */

// ---------------------------------------------------------------------------
// Kernel 1: fp32 GEMM  raw[m][n] += sum_k x[m][k] * W[n][k]   (split-K atomic)
// 256 threads, 128x128 tile, 8x8 micro-tile, BK=32, LDS transposed + pad 4.
// ---------------------------------------------------------------------------
__global__ __launch_bounds__(256) void gemm_raw(const float* __restrict__ X,
                                                const float* __restrict__ Wt,
                                                float* __restrict__ out) {
    __shared__ __align__(16) float As[BK][BM + 4];
    __shared__ __align__(16) float Bs[BK][BN + 4];
    const int tid = threadIdx.x;
    const int tx = tid & 15;   // column group 0..15
    const int ty = tid >> 4;   // row group 0..15
    const int m0 = blockIdx.y * BM;
    const int n0 = blockIdx.x * BN;
    const int kbeg = blockIdx.z * KLEN;

    float acc[8][8];
#pragma unroll
    for (int i = 0; i < 8; ++i)
#pragma unroll
        for (int j = 0; j < 8; ++j) acc[i][j] = 0.0f;

    for (int kt = 0; kt < KLEN / BK; ++kt) {
        const int k0 = kbeg + kt * BK;
        // stage 128x32 tiles of X and W (transposed into LDS: As[k][row])
#pragma unroll
        for (int p = 0; p < 4; ++p) {
            const int idx = tid + p * 256;
            const int row = idx >> 3;        // 0..127
            const int c4  = (idx & 7) * 4;   // 0,4,..,28
            const float4 va = *(const float4*)&X[(size_t)(m0 + row) * IN_F + k0 + c4];
            const float4 vb = *(const float4*)&Wt[(size_t)(n0 + row) * IN_F + k0 + c4];
            As[c4 + 0][row] = va.x; As[c4 + 1][row] = va.y;
            As[c4 + 2][row] = va.z; As[c4 + 3][row] = va.w;
            Bs[c4 + 0][row] = vb.x; Bs[c4 + 1][row] = vb.y;
            Bs[c4 + 2][row] = vb.z; Bs[c4 + 3][row] = vb.w;
        }
        __syncthreads();
#pragma unroll 4
        for (int k = 0; k < BK; ++k) {
            const float4 a0 = *(const float4*)&As[k][ty * 4];
            const float4 a1 = *(const float4*)&As[k][ty * 4 + 64];
            const float4 b0 = *(const float4*)&Bs[k][tx * 4];
            const float4 b1 = *(const float4*)&Bs[k][tx * 4 + 64];
            const float a[8] = {a0.x, a0.y, a0.z, a0.w, a1.x, a1.y, a1.z, a1.w};
            const float b[8] = {b0.x, b0.y, b0.z, b0.w, b1.x, b1.y, b1.z, b1.w};
#pragma unroll
            for (int i = 0; i < 8; ++i)
#pragma unroll
                for (int j = 0; j < 8; ++j) acc[i][j] += a[i] * b[j];
        }
        __syncthreads();
    }

#pragma unroll
    for (int i = 0; i < 8; ++i) {
        const int r = m0 + ty * 4 + (i & 3) + (i >> 2) * 64;
#pragma unroll
        for (int j = 0; j < 8; ++j) {
            const int c = n0 + tx * 4 + (j & 3) + (j >> 2) * 64;
            atomicAdd(&out[(size_t)r * OUT_F + c], acc[i][j]);
        }
    }
}

// ---------------------------------------------------------------------------
// Kernel 2: fused bias + LayerNorm + tanh*|mag| + 8-step Izhikevich SNN.
// One 1024-thread block per batch row; 4 neurons per thread; in-place on raw.
// ---------------------------------------------------------------------------
__global__ __launch_bounds__(1024) void snn_fused(float* __restrict__ raw,
                                                  const float* __restrict__ bias,
                                                  const float* __restrict__ gamma,
                                                  const float* __restrict__ beta,
                                                  const float* __restrict__ cmag,
                                                  const float* __restrict__ noise) {
    const int row = blockIdx.x;
    const int tid = threadIdx.x;
    const int col = tid * 4;
    __shared__ float red[16];

    float4 r = *(const float4*)&raw[(size_t)row * OUT_F + col];
    const float4 bb = *(const float4*)&bias[col];
    r.x += bb.x; r.y += bb.y; r.z += bb.z; r.w += bb.w;

    // ---- mean ----
    float s = (r.x + r.y) + (r.z + r.w);
#pragma unroll
    for (int off = 32; off; off >>= 1) s += __shfl_xor(s, off);
    if ((tid & 63) == 0) red[tid >> 6] = s;
    __syncthreads();
    if (tid < 16) {
        float t = red[tid];
        t += __shfl_xor(t, 8); t += __shfl_xor(t, 4);
        t += __shfl_xor(t, 2); t += __shfl_xor(t, 1);
        if (tid == 0) red[0] = t;
    }
    __syncthreads();
    const float mu = red[0] * (1.0f / (float)OUT_F);
    const float dx0 = r.x - mu, dx1 = r.y - mu, dx2 = r.z - mu, dx3 = r.w - mu;
    __syncthreads();  // everyone has read red[0]; safe to reuse

    // ---- variance ----
    float q = (dx0 * dx0 + dx1 * dx1) + (dx2 * dx2 + dx3 * dx3);
#pragma unroll
    for (int off = 32; off; off >>= 1) q += __shfl_xor(q, off);
    if ((tid & 63) == 0) red[tid >> 6] = q;
    __syncthreads();
    if (tid < 16) {
        float t = red[tid];
        t += __shfl_xor(t, 8); t += __shfl_xor(t, 4);
        t += __shfl_xor(t, 2); t += __shfl_xor(t, 1);
        if (tid == 0) red[0] = t;
    }
    __syncthreads();
    const float var = red[0] * (1.0f / (float)OUT_F);
    const float scale = 1.0f / sqrtf(var + 1e-5f);

    const float4 g  = *(const float4*)&gamma[col];
    const float4 be = *(const float4*)&beta[col];
    const float mag = fabsf(cmag[0]);

    float I[4];
    I[0] = tanhf(dx0 * scale * g.x + be.x) * mag;
    I[1] = tanhf(dx1 * scale * g.y + be.y) * mag;
    I[2] = tanhf(dx2 * scale * g.z + be.z) * mag;
    I[3] = tanhf(dx3 * scale * g.w + be.w) * mag;

    float v[4], u[4];
    int cnt[4];
#pragma unroll
    for (int j = 0; j < 4; ++j) { v[j] = -65.0f; u[j] = -13.0f; cnt[j] = 0; }

    for (int t = 0; t < TSTEPS; ++t) {
        const float4 nz =
            *(const float4*)&noise[(((size_t)t * BATCH) + row) * OUT_F + col];
        const float nn[4] = {nz.x, nz.y, nz.z, nz.w};
#pragma unroll
        for (int j = 0; j < 4; ++j) {
            const float It = I[j] + 0.3f * nn[j];
            const float vv = v[j];
            const float dv = (0.04f * vv * vv + 5.0f * vv + 140.0f - u[j] + It) * 0.5f;
            const float du = 0.02f * (0.2f * vv - u[j]) * 0.5f;
            float vn = vv + dv;
            vn = fminf(fmaxf(vn, -100.0f), 60.0f);
            float un = u[j] + du;
            un = fminf(fmaxf(un, -100.0f), 100.0f);
            const bool sp = (vn >= 30.0f);
            v[j] = sp ? -65.0f : vn;
            u[j] = sp ? (un + 8.0f) : un;
            cnt[j] += sp ? 1 : 0;
        }
    }

    float4 o;
    o.x = (float)cnt[0] * 0.125f;
    o.y = (float)cnt[1] * 0.125f;
    o.z = (float)cnt[2] * 0.125f;
    o.w = (float)cnt[3] * 0.125f;
    *(float4*)&raw[(size_t)row * OUT_F + col] = o;
}

extern "C" void kernel_launch(void* const* d_in, const int* in_sizes, int n_in,
                              void* d_out, int out_size, void* d_ws, size_t ws_size,
                              hipStream_t stream) {
    const float* x    = (const float*)d_in[0];
    const float* W    = (const float*)d_in[1];
    const float* b    = (const float*)d_in[2];
    const float* gam  = (const float*)d_in[3];
    const float* bet  = (const float*)d_in[4];
    const float* cmag = (const float*)d_in[5];
    const float* nz   = (const float*)d_in[6];
    float* out = (float*)d_out;

    // d_out doubles as the raw-GEMM accumulator (split-K atomics need zeros)
    hipMemsetAsync(out, 0, (size_t)BATCH * OUT_F * sizeof(float), stream);

    dim3 grid1(OUT_F / BN, BATCH / BM, KSPLIT);
    gemm_raw<<<grid1, 256, 0, stream>>>(x, W, out);

    snn_fused<<<BATCH, 1024, 0, stream>>>(out, b, gam, bet, cmag, nz);
}

// Round 2
// 180.310 us; speedup vs baseline: 2.0171x; 2.0171x over previous
//
#include <hip/hip_runtime.h>
#include <math.h>

#define IN_F 4096
#define OUT_F 4096
#define BATCH 256
#define TSTEPS 8

#define BM 128
#define BN 128
#define BK 32
#define KSPLIT 4
#define KLEN (IN_F / KSPLIT) /* 1024 */
#define NKT (KLEN / BK)      /* 32 */
#define LDA 40               /* padded fp16 row stride: 80B -> bank spread */

typedef _Float16 f16x8 __attribute__((ext_vector_type(8)));
typedef float f32x4 __attribute__((ext_vector_type(4)));

// Split one fp32 (pre-scaled x64) into two fp16 planes: v ~= h0 + h1*2^-11.
__device__ __forceinline__ void cvt8(const float4 a, const float4 b,
                                     f16x8& h0, f16x8& h1) {
  const float v[8] = {a.x, a.y, a.z, a.w, b.x, b.y, b.z, b.w};
#pragma unroll
  for (int j = 0; j < 8; ++j) {
    const float sv = v[j] * 64.0f;
    const _Float16 c0 = (_Float16)sv;
    const float r = (sv - (float)c0) * 2048.0f;
    h0[j] = c0;
    h1[j] = (_Float16)r;
  }
}

// ---------------------------------------------------------------------------
// fp16-split MFMA GEMM: out[m][n] += sum_k x[m][k]*W[n][k]  (split-K atomic)
// 128x128 tile, 4 waves x (64x64), 16x16x32 f16 MFMA, 3 MFMAs per logical.
// ---------------------------------------------------------------------------
__global__ __launch_bounds__(256, 1) void gemm_split(
    const float* __restrict__ X, const float* __restrict__ Wt,
    float* __restrict__ out) {
  __shared__ __align__(16) _Float16 A0s[BM][LDA];
  __shared__ __align__(16) _Float16 A1s[BM][LDA];
  __shared__ __align__(16) _Float16 B0s[BN][LDA];
  __shared__ __align__(16) _Float16 B1s[BN][LDA];

  const int tid = threadIdx.x;
  const int lane = tid & 63;
  const int w = tid >> 6;
  const int wr = w & 1;
  const int wc = w >> 1;
  const int lr = lane & 15;
  const int lk = lane >> 4;

  const int m0 = blockIdx.y * BM;
  const int n0 = blockIdx.x * BN;
  const int kbeg = blockIdx.z * KLEN;

  // staging: thread owns rows (tid>>2) and (tid>>2)+64, k-chunk (tid&3)*8
  const int srow = tid >> 2;
  const int sko = (tid & 3) * 8;
  const float* pa0 = X + (size_t)(m0 + srow) * IN_F + kbeg + sko;
  const float* pa1 = pa0 + (size_t)64 * IN_F;
  const float* pb0 = Wt + (size_t)(n0 + srow) * IN_F + kbeg + sko;
  const float* pb1 = pb0 + (size_t)64 * IN_F;

  float4 ra[2][2], rb[2][2];
  ra[0][0] = *(const float4*)(pa0);
  ra[0][1] = *(const float4*)(pa0 + 4);
  ra[1][0] = *(const float4*)(pa1);
  ra[1][1] = *(const float4*)(pa1 + 4);
  rb[0][0] = *(const float4*)(pb0);
  rb[0][1] = *(const float4*)(pb0 + 4);
  rb[1][0] = *(const float4*)(pb1);
  rb[1][1] = *(const float4*)(pb1 + 4);

  f32x4 acc0[4][4], acc1[4][4];
#pragma unroll
  for (int i = 0; i < 4; ++i)
#pragma unroll
    for (int j = 0; j < 4; ++j) {
      acc0[i][j] = (f32x4){0.f, 0.f, 0.f, 0.f};
      acc1[i][j] = (f32x4){0.f, 0.f, 0.f, 0.f};
    }

  for (int kt = 0; kt < NKT; ++kt) {
    __syncthreads();  // prev iteration's LDS reads done
    f16x8 h0, h1;
    cvt8(ra[0][0], ra[0][1], h0, h1);
    *(f16x8*)&A0s[srow][sko] = h0;
    *(f16x8*)&A1s[srow][sko] = h1;
    cvt8(ra[1][0], ra[1][1], h0, h1);
    *(f16x8*)&A0s[srow + 64][sko] = h0;
    *(f16x8*)&A1s[srow + 64][sko] = h1;
    cvt8(rb[0][0], rb[0][1], h0, h1);
    *(f16x8*)&B0s[srow][sko] = h0;
    *(f16x8*)&B1s[srow][sko] = h1;
    cvt8(rb[1][0], rb[1][1], h0, h1);
    *(f16x8*)&B0s[srow + 64][sko] = h0;
    *(f16x8*)&B1s[srow + 64][sko] = h1;
    __syncthreads();

    // prefetch next k-tile into registers; latency hides under MFMAs below
    if (kt + 1 < NKT) {
      const int ko = (kt + 1) * BK;
      ra[0][0] = *(const float4*)(pa0 + ko);
      ra[0][1] = *(const float4*)(pa0 + ko + 4);
      ra[1][0] = *(const float4*)(pa1 + ko);
      ra[1][1] = *(const float4*)(pa1 + ko + 4);
      rb[0][0] = *(const float4*)(pb0 + ko);
      rb[0][1] = *(const float4*)(pb0 + ko + 4);
      rb[1][0] = *(const float4*)(pb1 + ko);
      rb[1][1] = *(const float4*)(pb1 + ko + 4);
    }

    f16x8 fa0[4], fa1[4];
#pragma unroll
    for (int i = 0; i < 4; ++i) {
      fa0[i] = *(const f16x8*)&A0s[wr * 64 + i * 16 + lr][lk * 8];
      fa1[i] = *(const f16x8*)&A1s[wr * 64 + i * 16 + lr][lk * 8];
    }
#pragma unroll
    for (int j = 0; j < 4; ++j) {
      const f16x8 fb0 = *(const f16x8*)&B0s[wc * 64 + j * 16 + lr][lk * 8];
      const f16x8 fb1 = *(const f16x8*)&B1s[wc * 64 + j * 16 + lr][lk * 8];
#pragma unroll
      for (int i = 0; i < 4; ++i) {
        acc0[i][j] = __builtin_amdgcn_mfma_f32_16x16x32_f16(fa0[i], fb0, acc0[i][j], 0, 0, 0);
        acc1[i][j] = __builtin_amdgcn_mfma_f32_16x16x32_f16(fa0[i], fb1, acc1[i][j], 0, 0, 0);
        acc1[i][j] = __builtin_amdgcn_mfma_f32_16x16x32_f16(fa1[i], fb0, acc1[i][j], 0, 0, 0);
      }
    }
  }

  // epilogue: C/D layout col=lane&15, row=(lane>>4)*4+reg (m89-verified)
#pragma unroll
  for (int i = 0; i < 4; ++i) {
    const int rbase = m0 + wr * 64 + i * 16 + lk * 4;
#pragma unroll
    for (int j = 0; j < 4; ++j) {
      const int c = n0 + wc * 64 + j * 16 + lr;
#pragma unroll
      for (int r = 0; r < 4; ++r) {
        const float val = acc0[i][j][r] * 2.44140625e-4f /* 2^-12 */ +
                          acc1[i][j][r] * 1.1920928955078125e-7f /* 2^-23 */;
        atomicAdd(&out[(size_t)(rbase + r) * OUT_F + c], val);
      }
    }
  }
}

// ---------------------------------------------------------------------------
// Fused bias + LayerNorm + tanh*|mag| + 8-step Izhikevich. 512 thr/row.
// Single-pass sum/sumsq reduction (E[x^2]-mu^2).
// ---------------------------------------------------------------------------
__global__ __launch_bounds__(512) void snn_fused(
    float* __restrict__ raw, const float* __restrict__ bias,
    const float* __restrict__ gamma, const float* __restrict__ beta,
    const float* __restrict__ cmag, const float* __restrict__ noise) {
  const int row = blockIdx.x;
  const int tid = threadIdx.x;
  const int lane = tid & 63;
  const int wid = tid >> 6;
  const int col = tid * 8;
  __shared__ float redS[8], redQ[8];

  float x[8];
#pragma unroll
  for (int p = 0; p < 2; ++p) {
    const float4 rv = *(const float4*)&raw[(size_t)row * OUT_F + col + p * 4];
    const float4 bv = *(const float4*)&bias[col + p * 4];
    x[p * 4 + 0] = rv.x + bv.x;
    x[p * 4 + 1] = rv.y + bv.y;
    x[p * 4 + 2] = rv.z + bv.z;
    x[p * 4 + 3] = rv.w + bv.w;
  }
  float s = 0.f, q = 0.f;
#pragma unroll
  for (int e = 0; e < 8; ++e) {
    s += x[e];
    q += x[e] * x[e];
  }
#pragma unroll
  for (int off = 32; off; off >>= 1) {
    s += __shfl_xor(s, off);
    q += __shfl_xor(q, off);
  }
  if (lane == 0) {
    redS[wid] = s;
    redQ[wid] = q;
  }
  __syncthreads();
  s = 0.f;
  q = 0.f;
#pragma unroll
  for (int wv = 0; wv < 8; ++wv) {
    s += redS[wv];
    q += redQ[wv];
  }
  const float mu = s * (1.0f / (float)OUT_F);
  const float var = q * (1.0f / (float)OUT_F) - mu * mu;
  const float sc = 1.0f / sqrtf(var + 1e-5f);
  const float mag = fabsf(cmag[0]);

  float I[8];
#pragma unroll
  for (int p = 0; p < 2; ++p) {
    const float4 g = *(const float4*)&gamma[col + p * 4];
    const float4 be = *(const float4*)&beta[col + p * 4];
    I[p * 4 + 0] = tanhf((x[p * 4 + 0] - mu) * sc * g.x + be.x) * mag;
    I[p * 4 + 1] = tanhf((x[p * 4 + 1] - mu) * sc * g.y + be.y) * mag;
    I[p * 4 + 2] = tanhf((x[p * 4 + 2] - mu) * sc * g.z + be.z) * mag;
    I[p * 4 + 3] = tanhf((x[p * 4 + 3] - mu) * sc * g.w + be.w) * mag;
  }

  float v[8], u[8];
  int cnt[8];
#pragma unroll
  for (int j = 0; j < 8; ++j) {
    v[j] = -65.0f;
    u[j] = -13.0f;
    cnt[j] = 0;
  }

#pragma unroll
  for (int t = 0; t < TSTEPS; ++t) {
    float nn[8];
#pragma unroll
    for (int p = 0; p < 2; ++p) {
      const float4 nz = *(const float4*)&noise[(((size_t)t * BATCH) + row) * OUT_F + col + p * 4];
      nn[p * 4 + 0] = nz.x;
      nn[p * 4 + 1] = nz.y;
      nn[p * 4 + 2] = nz.z;
      nn[p * 4 + 3] = nz.w;
    }
#pragma unroll
    for (int j = 0; j < 8; ++j) {
      const float It = I[j] + 0.3f * nn[j];
      const float vv = v[j];
      const float dv = (0.04f * vv * vv + 5.0f * vv + 140.0f - u[j] + It) * 0.5f;
      const float du = 0.02f * (0.2f * vv - u[j]) * 0.5f;
      float vn = vv + dv;
      vn = fminf(fmaxf(vn, -100.0f), 60.0f);
      float un = u[j] + du;
      un = fminf(fmaxf(un, -100.0f), 100.0f);
      const bool sp = (vn >= 30.0f);
      v[j] = sp ? -65.0f : vn;
      u[j] = sp ? (un + 8.0f) : un;
      cnt[j] += sp ? 1 : 0;
    }
  }

#pragma unroll
  for (int p = 0; p < 2; ++p) {
    float4 o;
    o.x = (float)cnt[p * 4 + 0] * 0.125f;
    o.y = (float)cnt[p * 4 + 1] * 0.125f;
    o.z = (float)cnt[p * 4 + 2] * 0.125f;
    o.w = (float)cnt[p * 4 + 3] * 0.125f;
    *(float4*)&raw[(size_t)row * OUT_F + col + p * 4] = o;
  }
}

extern "C" void kernel_launch(void* const* d_in, const int* in_sizes, int n_in,
                              void* d_out, int out_size, void* d_ws, size_t ws_size,
                              hipStream_t stream) {
  const float* x = (const float*)d_in[0];
  const float* W = (const float*)d_in[1];
  const float* b = (const float*)d_in[2];
  const float* gam = (const float*)d_in[3];
  const float* bet = (const float*)d_in[4];
  const float* cmag = (const float*)d_in[5];
  const float* nz = (const float*)d_in[6];
  float* out = (float*)d_out;
  (void)d_ws;
  (void)ws_size;

  // d_out doubles as the raw-GEMM accumulator (split-K atomics need zeros)
  hipMemsetAsync(out, 0, (size_t)BATCH * OUT_F * sizeof(float), stream);

  dim3 grid1(OUT_F / BN, BATCH / BM, KSPLIT);
  gemm_split<<<grid1, 256, 0, stream>>>(x, W, out);

  snn_fused<<<BATCH, 512, 0, stream>>>(out, b, gam, bet, cmag, nz);
}